// Round 2
// baseline (5119.343 us; speedup 1.0000x reference)
//
#include <hip/hip_runtime.h>
#include <stdint.h>
#include <stddef.h>

// Variational-dropout LSTM, SEQ=256, B=64, IN=H=1024, fp32 I/O.
//
// R5: R4's persistent kernel, but the per-step mh broadcast now goes through
// the per-XCD L2 instead of 8B bypass atomics. Protocol per step:
//   x-proj MFMAs (static Ap, overlaps other blocks' tails)
//   wave0 polls flags (bypass atomic loads) -> gate __syncthreads
//   ALL waves: acquire-agent fence (s_waitcnt + buffer_inv sc1)
//   plain cached bf16x8 mh loads (first block/XCD refills L2 from MALL,
//   the other 31 blocks hit L2)  -> 32x less MALL read traffic
//   MFMA, LDS reduce, cell epilogue, sc1 write-through mh stores,
//   barrier (drains every wave's stores), flag release (vmcnt(0)+sc0 sc1).
// Fallback (small ws): R3's per-step launch path, unchanged.

#define SEQ 256

typedef __attribute__((ext_vector_type(8))) __bf16 bf16x8;
typedef __attribute__((ext_vector_type(4))) float  f32x4;
typedef __attribute__((ext_vector_type(4))) _Float16 f16x4;
typedef unsigned short u16;
typedef unsigned int   u32;
typedef unsigned long long u64;

__device__ __forceinline__ u16 f2bf(float f) {
  union { float f; unsigned u; } v; v.f = f;
  unsigned r = v.u + 0x7FFFu + ((v.u >> 16) & 1u);   // RNE
  return (u16)(r >> 16);
}
__device__ __forceinline__ float sigm(float x) {
  return __builtin_amdgcn_rcpf(1.f + __expf(-x));
}
__device__ __forceinline__ float tanh_fast(float x) {
  float xc = fminf(15.f, fmaxf(-15.f, x));
  float t = __expf(-2.f * xc);
  return (1.f - t) * __builtin_amdgcn_rcpf(1.f + t);
}
__device__ __forceinline__ float pick4(int idx, float v0, float v1, float v2, float v3) {
  float lo = (idx & 1) ? v1 : v0;
  float hi = (idx & 1) ? v3 : v2;
  return (idx & 2) ? hi : lo;
}

// ws layout (bytes):
//  Wihp @ 0         : [bk 256][kcw 32][l 64][e 8] bf16 = 8388608
//  Whhp @ 8388608   : same = 8388608
//  Ap   @ 16777216  : [s 256][m 4][kwg 32][l 64][e 8] bf16 = 33554432
//  mh0  @ 50331648  : [m 4][kwg 32][l 64][e 8] bf16 = 131072
//  mh1  @ 50462720  : 131072
//  bias @ 50593792  : 4096 f32 = 16384
//  c    @ 50610176  : [b 64][col 1024] f32 = 262144   (fallback path only)
//  flags@ 50872320  : 256 u32 = 1024                  (end: 50873344)

__global__ __launch_bounds__(256) void prep_kernel(
    const float* __restrict__ x, const float* __restrict__ h0,
    const float* __restrict__ c0, const float* __restrict__ mask_x,
    const float* __restrict__ mask_h, const float* __restrict__ Wih,
    const float* __restrict__ Whh, const float* __restrict__ bih,
    const float* __restrict__ bhh,
    u16* __restrict__ Wihp, u16* __restrict__ Whhp, u16* __restrict__ Ap,
    u16* __restrict__ mhp0, float* __restrict__ bias, float* __restrict__ c,
    u32* __restrict__ flags, int persist)
{
  const unsigned idx = blockIdx.x * 256u + threadIdx.x;  // 0 .. 16777215

  // Ap[s][m][kwg][l][e] = bf16( x[s][b][k] * mask_x[b][k] )
  {
    const unsigned e   = idx & 7u;
    const unsigned l   = (idx >> 3) & 63u;
    const unsigned kwg = (idx >> 9) & 31u;
    const unsigned m   = (idx >> 14) & 3u;
    const unsigned s   = idx >> 16;
    const unsigned b   = m * 16u + (l & 15u);
    const unsigned k   = kwg * 32u + (l >> 4) * 8u + e;
    Ap[idx] = f2bf(x[((size_t)s * 64u + b) * 1024u + k] * mask_x[b * 1024u + k]);
  }
  // W swizzles: [bk][kcw][l][e], n = (nl&3)*1024 + bk*4 + (nl>>2)
  if (idx < 4194304u) {
    const unsigned e   = idx & 7u;
    const unsigned l   = (idx >> 3) & 63u;
    const unsigned kcw = (idx >> 9) & 31u;
    const unsigned bk  = idx >> 14;
    const unsigned nl  = l & 15u;
    const unsigned n   = (nl & 3u) * 1024u + bk * 4u + (nl >> 2);
    const unsigned k   = kcw * 32u + (l >> 4) * 8u + e;
    Wihp[idx] = f2bf(Wih[n * 1024u + k]);
    Whhp[idx] = f2bf(Whh[n * 1024u + k]);
  }
  // mh0[m][kwg][l][e] = bf16(h0 * mask_h), plus c init (fallback path)
  if (idx < 65536u) {
    const unsigned e   = idx & 7u;
    const unsigned l   = (idx >> 3) & 63u;
    const unsigned kwg = (idx >> 9) & 31u;
    const unsigned m   = idx >> 14;
    const unsigned b   = m * 16u + (l & 15u);
    const unsigned k   = kwg * 32u + (l >> 4) * 8u + e;
    mhp0[idx] = f2bf(h0[b * 1024u + k] * mask_h[b * 1024u + k]);
    c[idx] = c0[idx];
  }
  if (idx < 4096u) bias[idx] = bih[idx] + bhh[idx];
  if (persist && idx < 256u) flags[idx] = 0u;
}

// ---------------------------------------------------------------------------
// Persistent recurrence kernel: 256 blocks x 512 threads, all 256 steps.
// Block bk owns h-cols [bk*4, bk*4+4) (gate-interleaved, 16 N-fragment cols).
// Wave w (0..7) owns K-slice [w*128, (w+1)*128).
// ---------------------------------------------------------------------------
__global__ __launch_bounds__(512, 2) void lstm_persist(
    const u16* __restrict__ Ap, const u16* __restrict__ Wihp,
    const u16* __restrict__ Whhp, const float* __restrict__ bias,
    const float* __restrict__ c0, const float* __restrict__ mask_h,
    u16* __restrict__ mh0, u16* __restrict__ mh1,
    u32* __restrict__ flags, float* __restrict__ out)
{
  __shared__ f32x4 lds[8][4][64];   // [w][m][l] 32 KB

  const int tid = threadIdx.x;
  const int w   = tid >> 6;       // K-slice 0..7
  const int l   = tid & 63;
  const int bk  = blockIdx.x;

  const bf16x8* WHV = (const bf16x8*)Whhp;
  const bf16x8* WIV = (const bf16x8*)Wihp;
  const bf16x8* ApV = (const bf16x8*)Ap;

  // Weights resident in registers for the whole sequence.
  bf16x8 wh[4], wi[4];
  #pragma unroll
  for (int kw = 0; kw < 4; ++kw) {
    wh[kw] = WHV[(bk * 32 + w * 4 + kw) * 64 + l];
    wi[kw] = WIV[(bk * 32 + w * 4 + kw) * 64 + l];
  }

  const int nl     = l & 15;
  const int quad   = l >> 4;
  const int g_role = nl & 3;
  const int jh     = nl >> 2;
  const int col_h  = bk * 4 + jh;

  // Cell state + per-lane constants in registers (epilogue waves only).
  float bias_reg = 0.f;
  float c_reg[4]    = {0.f, 0.f, 0.f, 0.f};
  float mask_reg[4] = {0.f, 0.f, 0.f, 0.f};
  if (w < 4) {
    bias_reg = bias[g_role * 1024 + col_h];
    #pragma unroll
    for (int r = 0; r < 4; ++r) {
      const int row = w * 16 + quad * 4 + r;
      c_reg[r]    = c0[row * 1024 + col_h];
      mask_reg[r] = mask_h[row * 1024 + col_h];
    }
  }

  // mh store address pieces (packed u64: block's 4 cols contiguous e).
  const int mh_lin_base = ((w * 32 + (bk >> 3)) * 64 + (((bk >> 1) & 3) * 16 + quad * 4)) * 8
                          + (bk & 1) * 4;   // + r*8 per r

  for (int s = 0; s < SEQ; ++s) {
    const u16* mi = (s & 1) ? mh1 : mh0;
    u16*       mo = (s & 1) ? mh0 : mh1;

    f32x4 acc[4];
    #pragma unroll
    for (int m = 0; m < 4; ++m) acc[m] = (f32x4){0.f, 0.f, 0.f, 0.f};

    // ---- x-projection part: no cross-step dependency; runs while other
    // blocks are still finishing step s-1 (their flags not yet set).
    #pragma unroll
    for (int kw = 0; kw < 4; ++kw) {
      bf16x8 a[4];
      #pragma unroll
      for (int m = 0; m < 4; ++m)
        a[m] = ApV[((s * 4 + m) * 32 + w * 4 + kw) * 64 + l];
      #pragma unroll
      for (int m = 0; m < 4; ++m)
        acc[m] = __builtin_amdgcn_mfma_f32_16x16x32_bf16(a[m], wi[kw], acc[m], 0, 0, 0);
    }

    // ---- gate: wave 0 polls (bypass atomic loads), then all waves fence.
    if (s > 0) {
      if (w == 0) {
        const u32 target = (u32)s;
        int spins = 0;
        for (;;) {
          u32 f0 = __hip_atomic_load(&flags[l * 4 + 0], __ATOMIC_RELAXED, __HIP_MEMORY_SCOPE_AGENT);
          u32 f1 = __hip_atomic_load(&flags[l * 4 + 1], __ATOMIC_RELAXED, __HIP_MEMORY_SCOPE_AGENT);
          u32 f2 = __hip_atomic_load(&flags[l * 4 + 2], __ATOMIC_RELAXED, __HIP_MEMORY_SCOPE_AGENT);
          u32 f3 = __hip_atomic_load(&flags[l * 4 + 3], __ATOMIC_RELAXED, __HIP_MEMORY_SCOPE_AGENT);
          bool ok = (f0 >= target) & (f1 >= target) & (f2 >= target) & (f3 >= target);
          if (__all(ok)) break;
          if (++spins > (1 << 15)) break;   // failsafe: never hang the queue
          __builtin_amdgcn_s_sleep(1);
        }
      }
      __syncthreads();
      // Each wave invalidates stale L2 lines itself (buffer_inv sc1), so its
      // own subsequent loads are guaranteed to refill from the MALL.
      __builtin_amdgcn_fence(__ATOMIC_ACQUIRE, "agent");
    }

    // ---- recurrent part: PLAIN cached loads of mh fragments. First toucher
    // per XCD refills L2 from MALL; the other 31 blocks hit L2.
    const bf16x8* miv = (const bf16x8*)mi;
    bf16x8 hf[16];
    #pragma unroll
    for (int m = 0; m < 4; ++m)
      #pragma unroll
      for (int kw = 0; kw < 4; ++kw)
        hf[m * 4 + kw] = miv[(m * 32 + w * 4 + kw) * 64 + l];
    #pragma unroll
    for (int kw = 0; kw < 4; ++kw)
      #pragma unroll
      for (int m = 0; m < 4; ++m)
        acc[m] = __builtin_amdgcn_mfma_f32_16x16x32_bf16(hf[m * 4 + kw], wh[kw], acc[m], 0, 0, 0);

    #pragma unroll
    for (int m = 0; m < 4; ++m) lds[w][m][l] = acc[m];
    __syncthreads();   // #1: LDS writes -> reduce

    if (w < 4) {
      f32x4 t = lds[0][w][l];
      #pragma unroll
      for (int ww = 1; ww < 8; ++ww) t += lds[ww][w][l];

      #pragma unroll
      for (int r = 0; r < 4; ++r) {
        const int row = w * 16 + quad * 4 + r;
        const float gp = t[r] + bias_reg;
        const float v1 = __shfl_xor(gp, 1, 64);
        const float v2 = __shfl_xor(gp, 2, 64);
        const float v3 = __shfl_xor(gp, 3, 64);
        const float ig = pick4(g_role,     gp, v1, v2, v3);
        const float fg = pick4(g_role ^ 1, gp, v1, v2, v3);
        const float gg = pick4(g_role ^ 2, gp, v1, v2, v3);
        const float og = pick4(g_role ^ 3, gp, v1, v2, v3);
        const float iv = sigm(ig);
        const float fv = sigm(fg);
        const float gv = tanh_fast(gg);
        const float ov = sigm(og);
        const float cn = fv * c_reg[r] + iv * gv;
        c_reg[r] = cn;
        const float hn = ov * tanh_fast(cn);
        const float mv = hn * mask_reg[r];

        // gather the block's 4 h-cols into the jh==0 lanes (g_role==0)
        const float h1 = __shfl_xor(hn, 4, 64);
        const float h2 = __shfl_xor(hn, 8, 64);
        const float h3 = __shfl_xor(hn, 12, 64);
        const float m1 = __shfl_xor(mv, 4, 64);
        const float m2 = __shfl_xor(mv, 8, 64);
        const float m3 = __shfl_xor(mv, 12, 64);
        float cn1 = 0.f, cn2 = 0.f, cn3 = 0.f;
        if (s == SEQ - 1) {
          cn1 = __shfl_xor(cn, 4, 64);
          cn2 = __shfl_xor(cn, 8, 64);
          cn3 = __shfl_xor(cn, 12, 64);
        }
        if (nl == 0) {
          f32x4 ho = {hn, h1, h2, h3};
          *(f32x4*)&out[((size_t)s * 64 + row) * 1024 + bk * 4] = ho;
          const u64 pk = (u64)f2bf(mv) | ((u64)f2bf(m1) << 16)
                       | ((u64)f2bf(m2) << 32) | ((u64)f2bf(m3) << 48);
          __hip_atomic_store((u64*)&mo[mh_lin_base + r * 8], pk,
                             __ATOMIC_RELAXED, __HIP_MEMORY_SCOPE_AGENT);
          if (s == SEQ - 1) {
            f32x4 co = {cn, cn1, cn2, cn3};
            *(f32x4*)&out[16777216 + row * 1024 + bk * 4] = ho;            // h_n
            *(f32x4*)&out[16777216 + 65536 + row * 1024 + bk * 4] = co;    // c_n
          }
        }
      }
    }
    __syncthreads();   // #2: drains every wave's stores (vmcnt(0) pre-barrier)

    if (tid == 0 && s < SEQ - 1) {
      // Release this block's step: explicit drain + coherent flag store.
      u32 val  = (u32)(s + 1);
      u32 voff = (u32)(bk * 4);
      asm volatile("s_waitcnt vmcnt(0)\n\t"
                   "global_store_dword %0, %1, %2 sc0 sc1"
                   :: "v"(voff), "v"(val), "s"(flags) : "memory");
    }
  }
}

// ---------------------------------------------------------------------------
// Fallback per-step kernel (R3, unchanged): used only when ws is too small.
// ---------------------------------------------------------------------------
__global__ __launch_bounds__(256) void lstm_step(
    const u16* __restrict__ Ap,
    const u16* __restrict__ Wihp,
    const u16* __restrict__ Whhp,
    const _Float16* __restrict__ xg,  // null => fold x-GEMM
    const float* __restrict__ bias,
    const u16* __restrict__ mh_in, u16* __restrict__ mh_out,
    float* __restrict__ c, const float* __restrict__ mask_h,
    float* __restrict__ out, int s)
{
  __shared__ f32x4 lds[4][4][64];   // [w][m][l] 16 KB

  const int tid = threadIdx.x;
  const int w   = tid >> 6;      // K-slice
  const int l   = tid & 63;
  const int bk  = blockIdx.x;    // 4 h-cols

  const bf16x8* mb = (const bf16x8*)mh_in;
  const bf16x8* WH = (const bf16x8*)Whhp;

  f32x4 acc[4] = { {0,0,0,0}, {0,0,0,0}, {0,0,0,0}, {0,0,0,0} };

  #pragma unroll 2
  for (int kw = 0; kw < 8; ++kw) {
    bf16x8 b = WH[(bk * 32 + w * 8 + kw) * 64 + l];
    #pragma unroll
    for (int m = 0; m < 4; ++m) {
      bf16x8 a = mb[(m * 32 + w * 8 + kw) * 64 + l];
      acc[m] = __builtin_amdgcn_mfma_f32_16x16x32_bf16(a, b, acc[m], 0, 0, 0);
    }
  }
  if (xg == nullptr) {   // fold x-projection
    const bf16x8* ApV = (const bf16x8*)Ap;
    const bf16x8* WI  = (const bf16x8*)Wihp;
    #pragma unroll 2
    for (int kw = 0; kw < 8; ++kw) {
      bf16x8 b = WI[(bk * 32 + w * 8 + kw) * 64 + l];
      #pragma unroll
      for (int m = 0; m < 4; ++m) {
        bf16x8 a = ApV[((s * 4 + m) * 32 + w * 8 + kw) * 64 + l];
        acc[m] = __builtin_amdgcn_mfma_f32_16x16x32_bf16(a, b, acc[m], 0, 0, 0);
      }
    }
  }
  #pragma unroll
  for (int m = 0; m < 4; ++m) lds[w][m][l] = acc[m];
  __syncthreads();

  f32x4 t = lds[0][w][l];
  #pragma unroll
  for (int ww = 1; ww < 4; ++ww) t += lds[ww][w][l];

  const int nl     = l & 15;
  const int quad   = l >> 4;
  const int g_role = nl & 3;
  const int jh     = nl >> 2;
  const int col_h  = bk * 4 + jh;

  if (xg != nullptr) {
    f16x4 xv = *(const f16x4*)&xg[((((size_t)s * 256 + bk) * 4 + w) * 64 + l) * 4];
    #pragma unroll
    for (int r = 0; r < 4; ++r) t[r] += (float)xv[r];
  }
  const float bias_reg = bias[g_role * 1024 + col_h];
  const int kwg = col_h >> 5;
  const int lp  = ((col_h >> 3) & 3) * 16;

  #pragma unroll
  for (int r = 0; r < 4; ++r) {
    const int b_row = w * 16 + quad * 4 + r;
    const float gp = t[r] + bias_reg;
    const float v1 = __shfl_xor(gp, 1, 64);
    const float v2 = __shfl_xor(gp, 2, 64);
    const float v3 = __shfl_xor(gp, 3, 64);
    const float ig = pick4(g_role,     gp, v1, v2, v3);
    const float fg = pick4(g_role ^ 1, gp, v1, v2, v3);
    const float gg = pick4(g_role ^ 2, gp, v1, v2, v3);
    const float og = pick4(g_role ^ 3, gp, v1, v2, v3);
    const float iv = sigm(ig);
    const float fv = sigm(fg);
    const float gv = tanh_fast(gg);
    const float ov = sigm(og);
    const float cold = c[b_row * 1024 + col_h];
    const float cn = fv * cold + iv * gv;
    const float hn = ov * tanh_fast(cn);
    if (g_role == 0) {
      c[b_row * 1024 + col_h] = cn;
      out[((size_t)s * 64 + b_row) * 1024 + col_h] = hn;
      mh_out[((w * 32 + kwg) * 64 + (lp + (b_row & 15))) * 8 + (col_h & 7)] =
          f2bf(hn * mask_h[b_row * 1024 + col_h]);
      if (s == SEQ - 1) {
        out[16777216 + b_row * 1024 + col_h] = hn;           // h_n
        out[16777216 + 65536 + b_row * 1024 + col_h] = cn;   // c_n
      }
    }
  }
}

extern "C" void kernel_launch(void* const* d_in, const int* in_sizes, int n_in,
                              void* d_out, int out_size, void* d_ws, size_t ws_size,
                              hipStream_t stream)
{
  const float* x      = (const float*)d_in[0];
  const float* h0     = (const float*)d_in[1];
  const float* c0     = (const float*)d_in[2];
  const float* mask_x = (const float*)d_in[3];
  const float* mask_h = (const float*)d_in[4];
  const float* Wih    = (const float*)d_in[5];
  const float* Whh    = (const float*)d_in[6];
  const float* bih    = (const float*)d_in[7];
  const float* bhh    = (const float*)d_in[8];
  float* out = (float*)d_out;

  char* ws = (char*)d_ws;
  u16*   Wihp  = (u16*)(ws + 0);
  u16*   Whhp  = (u16*)(ws + 8388608);
  u16*   Ap    = (u16*)(ws + 16777216);
  u16*   mh0   = (u16*)(ws + 50331648);
  u16*   mh1   = (u16*)(ws + 50462720);
  float* bias  = (float*)(ws + 50593792);
  float* c     = (float*)(ws + 50610176);
  u32*   flags = (u32*)(ws + 50872320);
  const bool persist = (ws_size >= (size_t)50873344);

  hipLaunchKernelGGL(prep_kernel, dim3(65536), dim3(256), 0, stream,
                     x, h0, c0, mask_x, mask_h, Wih, Whh, bih, bhh,
                     Wihp, Whhp, Ap, mh0, bias, c, flags, (int)persist);

  if (persist) {
    hipLaunchKernelGGL(lstm_persist, dim3(256), dim3(512), 0, stream,
                       Ap, Wihp, Whhp, bias, c0, mask_h, mh0, mh1, flags, out);
  } else {
    for (int s = 0; s < SEQ; ++s) {
      const u16* mi = (s & 1) ? mh1 : mh0;
      u16*       mo = (s & 1) ? mh0 : mh1;
      hipLaunchKernelGGL(lstm_step, dim3(256), dim3(256), 0, stream,
                         Ap, Wihp, Whhp, (const _Float16*)nullptr, bias, mi, mo,
                         c, mask_h, out, s);
    }
  }
}

// Round 3
// 1495.963 us; speedup vs baseline: 3.4221x; 3.4221x over previous
//
#include <hip/hip_runtime.h>
#include <stdint.h>
#include <stddef.h>

// Variational-dropout LSTM, SEQ=256, B=64, IN=H=1024, fp32 I/O.
//
// R6: R4's persistent kernel (bypass mh loads, NO fences — R5's per-wave
// buffer_inv was a 3x regression) with three MALL-request cuts:
//  (1) mh loads: inline-asm global_load_dwordx4 sc0 sc1 (16B bypass loads,
//      half the request count of R4's 8B atomic-load pairs).
//  (2) poll: wave 0 only, one dwordx4 per lane covers all 256 flags
//      (~32x less poll traffic than R4's all-wave scalar polls), then a
//      gate __syncthreads.
//  (3) early release: epilogue waves store mh, vmcnt(0), arrive on an LDS
//      counter, THEN issue out stores; wave 7 releases the flag at count==4
//      so the HBM out-store drain is off the inter-block critical path.
// Fallback (small ws): R3's per-step launch path, unchanged.

#define SEQ 256

typedef __attribute__((ext_vector_type(8))) __bf16 bf16x8;
typedef __attribute__((ext_vector_type(4))) float  f32x4;
typedef __attribute__((ext_vector_type(4))) _Float16 f16x4;
typedef __attribute__((ext_vector_type(4))) unsigned int u32x4;
typedef unsigned short u16;
typedef unsigned int   u32;
typedef unsigned long long u64;

__device__ __forceinline__ u16 f2bf(float f) {
  union { float f; unsigned u; } v; v.f = f;
  unsigned r = v.u + 0x7FFFu + ((v.u >> 16) & 1u);   // RNE
  return (u16)(r >> 16);
}
__device__ __forceinline__ float sigm(float x) {
  return __builtin_amdgcn_rcpf(1.f + __expf(-x));
}
__device__ __forceinline__ float tanh_fast(float x) {
  float xc = fminf(15.f, fmaxf(-15.f, x));
  float t = __expf(-2.f * xc);
  return (1.f - t) * __builtin_amdgcn_rcpf(1.f + t);
}
__device__ __forceinline__ float pick4(int idx, float v0, float v1, float v2, float v3) {
  float lo = (idx & 1) ? v1 : v0;
  float hi = (idx & 1) ? v3 : v2;
  return (idx & 2) ? hi : lo;
}

// ws layout (bytes):
//  Wihp @ 0         : [bk 256][kcw 32][l 64][e 8] bf16 = 8388608
//  Whhp @ 8388608   : same = 8388608
//  Ap   @ 16777216  : [s 256][m 4][kwg 32][l 64][e 8] bf16 = 33554432
//  mh0  @ 50331648  : [m 4][kwg 32][l 64][e 8] bf16 = 131072
//  mh1  @ 50462720  : 131072
//  bias @ 50593792  : 4096 f32 = 16384
//  c    @ 50610176  : [b 64][col 1024] f32 = 262144   (fallback path only)
//  flags@ 50872320  : 256 u32 = 1024                  (end: 50873344)

__global__ __launch_bounds__(256) void prep_kernel(
    const float* __restrict__ x, const float* __restrict__ h0,
    const float* __restrict__ c0, const float* __restrict__ mask_x,
    const float* __restrict__ mask_h, const float* __restrict__ Wih,
    const float* __restrict__ Whh, const float* __restrict__ bih,
    const float* __restrict__ bhh,
    u16* __restrict__ Wihp, u16* __restrict__ Whhp, u16* __restrict__ Ap,
    u16* __restrict__ mhp0, float* __restrict__ bias, float* __restrict__ c,
    u32* __restrict__ flags, int persist)
{
  const unsigned idx = blockIdx.x * 256u + threadIdx.x;  // 0 .. 16777215

  // Ap[s][m][kwg][l][e] = bf16( x[s][b][k] * mask_x[b][k] )
  {
    const unsigned e   = idx & 7u;
    const unsigned l   = (idx >> 3) & 63u;
    const unsigned kwg = (idx >> 9) & 31u;
    const unsigned m   = (idx >> 14) & 3u;
    const unsigned s   = idx >> 16;
    const unsigned b   = m * 16u + (l & 15u);
    const unsigned k   = kwg * 32u + (l >> 4) * 8u + e;
    Ap[idx] = f2bf(x[((size_t)s * 64u + b) * 1024u + k] * mask_x[b * 1024u + k]);
  }
  // W swizzles: [bk][kcw][l][e], n = (nl&3)*1024 + bk*4 + (nl>>2)
  if (idx < 4194304u) {
    const unsigned e   = idx & 7u;
    const unsigned l   = (idx >> 3) & 63u;
    const unsigned kcw = (idx >> 9) & 31u;
    const unsigned bk  = idx >> 14;
    const unsigned nl  = l & 15u;
    const unsigned n   = (nl & 3u) * 1024u + bk * 4u + (nl >> 2);
    const unsigned k   = kcw * 32u + (l >> 4) * 8u + e;
    Wihp[idx] = f2bf(Wih[n * 1024u + k]);
    Whhp[idx] = f2bf(Whh[n * 1024u + k]);
  }
  // mh0[m][kwg][l][e] = bf16(h0 * mask_h), plus c init (fallback path)
  if (idx < 65536u) {
    const unsigned e   = idx & 7u;
    const unsigned l   = (idx >> 3) & 63u;
    const unsigned kwg = (idx >> 9) & 31u;
    const unsigned m   = idx >> 14;
    const unsigned b   = m * 16u + (l & 15u);
    const unsigned k   = kwg * 32u + (l >> 4) * 8u + e;
    mhp0[idx] = f2bf(h0[b * 1024u + k] * mask_h[b * 1024u + k]);
    c[idx] = c0[idx];
  }
  if (idx < 4096u) bias[idx] = bih[idx] + bhh[idx];
  if (persist && idx < 256u) flags[idx] = 0u;
}

// ---------------------------------------------------------------------------
// Persistent recurrence kernel: 256 blocks x 512 threads, all 256 steps.
// Block bk owns h-cols [bk*4, bk*4+4) (gate-interleaved, 16 N-fragment cols).
// Wave w (0..7) owns K-slice [w*128, (w+1)*128).
// ---------------------------------------------------------------------------
__global__ __launch_bounds__(512, 2) void lstm_persist(
    const u16* __restrict__ Ap, const u16* __restrict__ Wihp,
    const u16* __restrict__ Whhp, const float* __restrict__ bias,
    const float* __restrict__ c0, const float* __restrict__ mask_h,
    u16* __restrict__ mh0, u16* __restrict__ mh1,
    u32* __restrict__ flags, float* __restrict__ out)
{
  __shared__ f32x4 lds[8][4][64];   // [w][m][l] 32 KB
  __shared__ u32 cnt;               // epilogue arrive counter

  const int tid = threadIdx.x;
  const int w   = tid >> 6;       // K-slice 0..7
  const int l   = tid & 63;
  const int bk  = blockIdx.x;

  const bf16x8* WHV = (const bf16x8*)Whhp;
  const bf16x8* WIV = (const bf16x8*)Wihp;
  const bf16x8* ApV = (const bf16x8*)Ap;

  // Weights resident in registers for the whole sequence.
  bf16x8 wh[4], wi[4];
  #pragma unroll
  for (int kw = 0; kw < 4; ++kw) {
    wh[kw] = WHV[(bk * 32 + w * 4 + kw) * 64 + l];
    wi[kw] = WIV[(bk * 32 + w * 4 + kw) * 64 + l];
  }

  const int nl     = l & 15;
  const int quad   = l >> 4;
  const int g_role = nl & 3;
  const int jh     = nl >> 2;
  const int col_h  = bk * 4 + jh;

  // Cell state + per-lane constants in registers (epilogue waves only).
  float bias_reg = 0.f;
  float c_reg[4]    = {0.f, 0.f, 0.f, 0.f};
  float mask_reg[4] = {0.f, 0.f, 0.f, 0.f};
  if (w < 4) {
    bias_reg = bias[g_role * 1024 + col_h];
    #pragma unroll
    for (int r = 0; r < 4; ++r) {
      const int row = w * 16 + quad * 4 + r;
      c_reg[r]    = c0[row * 1024 + col_h];
      mask_reg[r] = mask_h[row * 1024 + col_h];
    }
  }

  // mh store address pieces (packed u64: block's 4 cols contiguous e).
  const int mh_lin_base = ((w * 32 + (bk >> 3)) * 64 + (((bk >> 1) & 3) * 16 + quad * 4)) * 8
                          + (bk & 1) * 4;   // + r*8 per r

  if (tid == 0) cnt = 0u;
  __syncthreads();

  for (int s = 0; s < SEQ; ++s) {
    const u16* mi = (s & 1) ? mh1 : mh0;
    u16*       mo = (s & 1) ? mh0 : mh1;

    f32x4 acc[4];
    #pragma unroll
    for (int m = 0; m < 4; ++m) acc[m] = (f32x4){0.f, 0.f, 0.f, 0.f};

    // ---- x-projection part: no cross-step dependency; runs while other
    // blocks are still finishing step s-1 (their flags not yet set).
    #pragma unroll
    for (int kw = 0; kw < 4; ++kw) {
      bf16x8 a[4];
      #pragma unroll
      for (int m = 0; m < 4; ++m)
        a[m] = ApV[((s * 4 + m) * 32 + w * 4 + kw) * 64 + l];
      #pragma unroll
      for (int m = 0; m < 4; ++m)
        acc[m] = __builtin_amdgcn_mfma_f32_16x16x32_bf16(a[m], wi[kw], acc[m], 0, 0, 0);
    }

    // ---- gate: wave 0 polls (one bypass dwordx4 per lane covers all 256
    // flags), then a barrier releases the whole block. No fences (R5 lesson).
    if (s > 0) {
      if (w == 0) {
        const u32 target = (u32)s;
        const u32 poff = (u32)(l * 16);
        int spins = 0;
        for (;;) {
          u32x4 f;
          asm volatile("global_load_dwordx4 %0, %1, %2 sc0 sc1\n\t"
                       "s_waitcnt vmcnt(0)"
                       : "=v"(f) : "v"(poff), "s"(flags) : "memory");
          bool ok = (f[0] >= target) & (f[1] >= target) &
                    (f[2] >= target) & (f[3] >= target);
          if (__all(ok)) break;
          if (++spins > (1 << 15)) break;   // failsafe: never hang the queue
          __builtin_amdgcn_s_sleep(1);
        }
      }
      __syncthreads();
    }

    // ---- recurrent part: 16B bypass loads (sc0 sc1) of mh fragments.
    union { u32x4 r; bf16x8 v; } hf[16];
    #pragma unroll
    for (int m = 0; m < 4; ++m)
      #pragma unroll
      for (int kw = 0; kw < 4; ++kw) {
        const u32 off = (u32)((m * 32 + w * 4 + kw) * 1024 + l * 16);
        asm volatile("global_load_dwordx4 %0, %1, %2 sc0 sc1"
                     : "=v"(hf[m * 4 + kw].r) : "v"(off), "s"(mi) : "memory");
      }
    asm volatile("s_waitcnt vmcnt(0)" ::: "memory");
    __builtin_amdgcn_sched_barrier(0);   // rule #18: pin MFMAs after the wait
    #pragma unroll
    for (int kw = 0; kw < 4; ++kw)
      #pragma unroll
      for (int m = 0; m < 4; ++m)
        acc[m] = __builtin_amdgcn_mfma_f32_16x16x32_bf16(hf[m * 4 + kw].v, wh[kw], acc[m], 0, 0, 0);

    #pragma unroll
    for (int m = 0; m < 4; ++m) lds[w][m][l] = acc[m];
    __syncthreads();   // #1: LDS writes -> reduce

    if (w < 4) {
      f32x4 t = lds[0][w][l];
      #pragma unroll
      for (int ww = 1; ww < 8; ++ww) t += lds[ww][w][l];

      f32x4 ho_s[4];
      f32x4 co_s[4];
      #pragma unroll
      for (int r = 0; r < 4; ++r) {
        const float gp = t[r] + bias_reg;
        const float v1 = __shfl_xor(gp, 1, 64);
        const float v2 = __shfl_xor(gp, 2, 64);
        const float v3 = __shfl_xor(gp, 3, 64);
        const float ig = pick4(g_role,     gp, v1, v2, v3);
        const float fg = pick4(g_role ^ 1, gp, v1, v2, v3);
        const float gg = pick4(g_role ^ 2, gp, v1, v2, v3);
        const float og = pick4(g_role ^ 3, gp, v1, v2, v3);
        const float iv = sigm(ig);
        const float fv = sigm(fg);
        const float gv = tanh_fast(gg);
        const float ov = sigm(og);
        const float cn = fv * c_reg[r] + iv * gv;
        c_reg[r] = cn;
        const float hn = ov * tanh_fast(cn);
        const float mv = hn * mask_reg[r];

        // gather the block's 4 h-cols into the jh==0 lanes (g_role==0)
        const float h1 = __shfl_xor(hn, 4, 64);
        const float h2 = __shfl_xor(hn, 8, 64);
        const float h3 = __shfl_xor(hn, 12, 64);
        const float m1 = __shfl_xor(mv, 4, 64);
        const float m2 = __shfl_xor(mv, 8, 64);
        const float m3 = __shfl_xor(mv, 12, 64);
        ho_s[r] = (f32x4){hn, h1, h2, h3};
        if (s == SEQ - 1) {
          const float cn1 = __shfl_xor(cn, 4, 64);
          const float cn2 = __shfl_xor(cn, 8, 64);
          const float cn3 = __shfl_xor(cn, 12, 64);
          co_s[r] = (f32x4){cn, cn1, cn2, cn3};
        }
        if (nl == 0) {
          // mh store FIRST (the only store other blocks wait on)
          const u64 pk = (u64)f2bf(mv) | ((u64)f2bf(m1) << 16)
                       | ((u64)f2bf(m2) << 32) | ((u64)f2bf(m3) << 48);
          __hip_atomic_store((u64*)&mo[mh_lin_base + r * 8], pk,
                             __ATOMIC_RELAXED, __HIP_MEMORY_SCOPE_AGENT);
        }
      }
      // drain mh stores, then arrive; out stores AFTER (off the critical path)
      asm volatile("s_waitcnt vmcnt(0)" ::: "memory");
      if (l == 0)
        __hip_atomic_fetch_add(&cnt, 1u, __ATOMIC_RELAXED, __HIP_MEMORY_SCOPE_WORKGROUP);
      if (nl == 0) {
        #pragma unroll
        for (int r = 0; r < 4; ++r) {
          const int row = w * 16 + quad * 4 + r;
          *(f32x4*)&out[((size_t)s * 64 + row) * 1024 + bk * 4] = ho_s[r];
          if (s == SEQ - 1) {
            *(f32x4*)&out[16777216 + row * 1024 + bk * 4] = ho_s[r];        // h_n
            *(f32x4*)&out[16777216 + 65536 + row * 1024 + bk * 4] = co_s[r];// c_n
          }
        }
      }
    } else if (w == 7 && l == 0 && s < SEQ - 1) {
      // waiter: release the flag as soon as all 4 epilogue waves' mh stores
      // are drained — HBM out-store drain stays off the inter-block path.
      int spins = 0;
      while (__hip_atomic_load(&cnt, __ATOMIC_RELAXED, __HIP_MEMORY_SCOPE_WORKGROUP) < 4u) {
        if (++spins > (1 << 20)) break;   // failsafe
      }
      __hip_atomic_store(&cnt, 0u, __ATOMIC_RELAXED, __HIP_MEMORY_SCOPE_WORKGROUP);
      u32 val  = (u32)(s + 1);
      u32 voff = (u32)(bk * 4);
      asm volatile("s_waitcnt vmcnt(0)\n\t"
                   "global_store_dword %0, %1, %2 sc0 sc1"
                   :: "v"(voff), "v"(val), "s"(flags) : "memory");
    }
    __syncthreads();   // #2: WAR protection for lds + step advance
  }
}

// ---------------------------------------------------------------------------
// Fallback per-step kernel (R3, unchanged): used only when ws is too small.
// ---------------------------------------------------------------------------
__global__ __launch_bounds__(256) void lstm_step(
    const u16* __restrict__ Ap,
    const u16* __restrict__ Wihp,
    const u16* __restrict__ Whhp,
    const _Float16* __restrict__ xg,  // null => fold x-GEMM
    const float* __restrict__ bias,
    const u16* __restrict__ mh_in, u16* __restrict__ mh_out,
    float* __restrict__ c, const float* __restrict__ mask_h,
    float* __restrict__ out, int s)
{
  __shared__ f32x4 lds[4][4][64];   // [w][m][l] 16 KB

  const int tid = threadIdx.x;
  const int w   = tid >> 6;      // K-slice
  const int l   = tid & 63;
  const int bk  = blockIdx.x;    // 4 h-cols

  const bf16x8* mb = (const bf16x8*)mh_in;
  const bf16x8* WH = (const bf16x8*)Whhp;

  f32x4 acc[4] = { {0,0,0,0}, {0,0,0,0}, {0,0,0,0}, {0,0,0,0} };

  #pragma unroll 2
  for (int kw = 0; kw < 8; ++kw) {
    bf16x8 b = WH[(bk * 32 + w * 8 + kw) * 64 + l];
    #pragma unroll
    for (int m = 0; m < 4; ++m) {
      bf16x8 a = mb[(m * 32 + w * 8 + kw) * 64 + l];
      acc[m] = __builtin_amdgcn_mfma_f32_16x16x32_bf16(a, b, acc[m], 0, 0, 0);
    }
  }
  if (xg == nullptr) {   // fold x-projection
    const bf16x8* ApV = (const bf16x8*)Ap;
    const bf16x8* WI  = (const bf16x8*)Wihp;
    #pragma unroll 2
    for (int kw = 0; kw < 8; ++kw) {
      bf16x8 b = WI[(bk * 32 + w * 8 + kw) * 64 + l];
      #pragma unroll
      for (int m = 0; m < 4; ++m) {
        bf16x8 a = ApV[((s * 4 + m) * 32 + w * 8 + kw) * 64 + l];
        acc[m] = __builtin_amdgcn_mfma_f32_16x16x32_bf16(a, b, acc[m], 0, 0, 0);
      }
    }
  }
  #pragma unroll
  for (int m = 0; m < 4; ++m) lds[w][m][l] = acc[m];
  __syncthreads();

  f32x4 t = lds[0][w][l];
  #pragma unroll
  for (int ww = 1; ww < 4; ++ww) t += lds[ww][w][l];

  const int nl     = l & 15;
  const int quad   = l >> 4;
  const int g_role = nl & 3;
  const int jh     = nl >> 2;
  const int col_h  = bk * 4 + jh;

  if (xg != nullptr) {
    f16x4 xv = *(const f16x4*)&xg[((((size_t)s * 256 + bk) * 4 + w) * 64 + l) * 4];
    #pragma unroll
    for (int r = 0; r < 4; ++r) t[r] += (float)xv[r];
  }
  const float bias_reg = bias[g_role * 1024 + col_h];
  const int kwg = col_h >> 5;
  const int lp  = ((col_h >> 3) & 3) * 16;

  #pragma unroll
  for (int r = 0; r < 4; ++r) {
    const int b_row = w * 16 + quad * 4 + r;
    const float gp = t[r] + bias_reg;
    const float v1 = __shfl_xor(gp, 1, 64);
    const float v2 = __shfl_xor(gp, 2, 64);
    const float v3 = __shfl_xor(gp, 3, 64);
    const float ig = pick4(g_role,     gp, v1, v2, v3);
    const float fg = pick4(g_role ^ 1, gp, v1, v2, v3);
    const float gg = pick4(g_role ^ 2, gp, v1, v2, v3);
    const float og = pick4(g_role ^ 3, gp, v1, v2, v3);
    const float iv = sigm(ig);
    const float fv = sigm(fg);
    const float gv = tanh_fast(gg);
    const float ov = sigm(og);
    const float cold = c[b_row * 1024 + col_h];
    const float cn = fv * cold + iv * gv;
    const float hn = ov * tanh_fast(cn);
    if (g_role == 0) {
      c[b_row * 1024 + col_h] = cn;
      out[((size_t)s * 64 + b_row) * 1024 + col_h] = hn;
      mh_out[((w * 32 + kwg) * 64 + (lp + (b_row & 15))) * 8 + (col_h & 7)] =
          f2bf(hn * mask_h[b_row * 1024 + col_h]);
      if (s == SEQ - 1) {
        out[16777216 + b_row * 1024 + col_h] = hn;           // h_n
        out[16777216 + 65536 + b_row * 1024 + col_h] = cn;   // c_n
      }
    }
  }
}

extern "C" void kernel_launch(void* const* d_in, const int* in_sizes, int n_in,
                              void* d_out, int out_size, void* d_ws, size_t ws_size,
                              hipStream_t stream)
{
  const float* x      = (const float*)d_in[0];
  const float* h0     = (const float*)d_in[1];
  const float* c0     = (const float*)d_in[2];
  const float* mask_x = (const float*)d_in[3];
  const float* mask_h = (const float*)d_in[4];
  const float* Wih    = (const float*)d_in[5];
  const float* Whh    = (const float*)d_in[6];
  const float* bih    = (const float*)d_in[7];
  const float* bhh    = (const float*)d_in[8];
  float* out = (float*)d_out;

  char* ws = (char*)d_ws;
  u16*   Wihp  = (u16*)(ws + 0);
  u16*   Whhp  = (u16*)(ws + 8388608);
  u16*   Ap    = (u16*)(ws + 16777216);
  u16*   mh0   = (u16*)(ws + 50331648);
  u16*   mh1   = (u16*)(ws + 50462720);
  float* bias  = (float*)(ws + 50593792);
  float* c     = (float*)(ws + 50610176);
  u32*   flags = (u32*)(ws + 50872320);
  const bool persist = (ws_size >= (size_t)50873344);

  hipLaunchKernelGGL(prep_kernel, dim3(65536), dim3(256), 0, stream,
                     x, h0, c0, mask_x, mask_h, Wih, Whh, bih, bhh,
                     Wihp, Whhp, Ap, mh0, bias, c, flags, (int)persist);

  if (persist) {
    hipLaunchKernelGGL(lstm_persist, dim3(256), dim3(512), 0, stream,
                       Ap, Wihp, Whhp, bias, c0, mask_h, mh0, mh1, flags, out);
  } else {
    for (int s = 0; s < SEQ; ++s) {
      const u16* mi = (s & 1) ? mh1 : mh0;
      u16*       mo = (s & 1) ? mh0 : mh1;
      hipLaunchKernelGGL(lstm_step, dim3(256), dim3(256), 0, stream,
                         Ap, Wihp, Whhp, (const _Float16*)nullptr, bias, mi, mo,
                         c, mask_h, out, s);
    }
  }
}